// Round 15
// baseline (1033.318 us; speedup 1.0000x reference)
//
#include <hip/hip_runtime.h>
#include <hip/hip_bf16.h>

#define SEQLEN 4096

typedef __bf16 bf16x8 __attribute__((ext_vector_type(8)));
typedef float f32x4 __attribute__((ext_vector_type(4)));
typedef __attribute__((ext_vector_type(8))) unsigned short u16x8;

__device__ inline float bf2f(unsigned short s) {
  union { unsigned u; float f; } t; t.u = ((unsigned)s) << 16; return t.f;
}
__device__ inline unsigned short f2bf(float f) {
  __hip_bfloat16 h = __float2bfloat16(f);
  return *reinterpret_cast<unsigned short*>(&h);
}

__device__ inline void gload_lds16(const void* g, void* l) {
  __builtin_amdgcn_global_load_lds(
      (const __attribute__((address_space(1))) unsigned int*)g,
      (__attribute__((address_space(3))) unsigned int*)l, 16, 0, 0);
}

// ---------------- fused conversion kernel (r10 verified) ----------------
__global__ void cvt_all(const float* __restrict__ x, const float* __restrict__ Wq,
                        const float* __restrict__ Wk, const float* __restrict__ Wv,
                        const float* __restrict__ Wo,
                        const float* __restrict__ bq, const float* __restrict__ bk,
                        const float* __restrict__ bv,
                        unsigned short* __restrict__ Xb,
                        unsigned short* __restrict__ Wqkv,
                        unsigned short* __restrict__ WoB, float* __restrict__ Bqkv) {
  long i = (long)blockIdx.x * 256 + threadIdx.x;
  const float* src;
  unsigned short* dst;
  long rel;
  if (i < 4194304) {            // x -> Xb
    src = x; dst = Xb; rel = i;
  } else if (i < 4456448) {     // Wq
    src = Wq; dst = Wqkv; rel = i - 4194304;
  } else if (i < 4718592) {     // Wk
    src = Wk; dst = Wqkv + 1048576; rel = i - 4456448;
  } else if (i < 4980736) {     // Wv
    src = Wv; dst = Wqkv + 2097152; rel = i - 4718592;
  } else if (i < 5242880) {     // Wo
    src = Wo; dst = WoB; rel = i - 4980736;
  } else if (i < 5243648) {     // bias pack
    long j = i - 5242880;
    const float* bsrc = (j < 256) ? bq : (j < 512) ? bk : bv;
    long jr = j & 255;
    reinterpret_cast<float4*>(Bqkv)[j] =
        reinterpret_cast<const float4*>(bsrc)[jr];
    return;
  } else {
    return;
  }
  float4 v = reinterpret_cast<const float4*>(src)[rel];
  ushort4 o;
  o.x = f2bf(v.x); o.y = f2bf(v.y); o.z = f2bf(v.z); o.w = f2bf(v.w);
  reinterpret_cast<ushort4*>(dst)[rel] = o;
}

// ======= gemm32: 256x256 tile, BK=32, 64 KiB LDS -> 2 blocks/CU (QKV) =======
// Same fragment/epilogue math as verified gemm8p; K-tile halved so two
// independent blocks co-reside per CU (cross-block pipe overlap).
// LDS: A buf0 @0, A buf1 @8192, B buf0 @16384, B buf1 @24576 (ushort idx).
// Swizzle: slot (row,g) holds global granule g^((row>>1)&3), both sides.
__global__ __launch_bounds__(512, 4) void gemm32(
    const unsigned short* __restrict__ A, const unsigned short* __restrict__ B,
    const float* __restrict__ bias, unsigned short* __restrict__ C,
    int M, int N, int K, int ldc) {
  extern __shared__ __align__(16) unsigned short lds[];

  const int tid = threadIdx.x;
  const int lane = tid & 63, wv = tid >> 6;
  const int wr = wv >> 2, wc = wv & 3;
  const int r16 = lane & 15, kg = lane >> 4;
  const int sgA = kg ^ ((r16 >> 1) & 3);

  const int xcd = (int)blockIdx.x & 7;
  const int pos = (int)blockIdx.x >> 3;
  const int rpx = (M >> 8) >> 3;
  const int tile_m = xcd * rpx + (pos % rpx);
  const int tile_n = pos / rpx;
  const int brow = tile_m << 8, bcol = tile_n << 8;

  const unsigned short* Ag = A + (size_t)brow * K;
  const unsigned short* Bg = B + (size_t)bcol * K;

  auto STGT = [&](int pb, int kt) {  // stage A+B tile (4 DMA instrs)
    unsigned short* ab = lds + (pb << 13);
    unsigned short* bb = lds + 16384 + (pb << 13);
#pragma unroll
    for (int it = 0; it < 2; ++it) {
      int f = it * 512 + tid;
      int row = f >> 2, g = f & 3;
      int sg2 = g ^ ((row >> 1) & 3);
      gload_lds16(Ag + (size_t)row * K + (size_t)kt * 32 + sg2 * 8,
                  ab + row * 32 + g * 8);
      gload_lds16(Bg + (size_t)row * K + (size_t)kt * 32 + sg2 * 8,
                  bb + row * 32 + g * 8);
    }
  };

  f32x4 acc[8][4];
#pragma unroll
  for (int m = 0; m < 8; ++m)
#pragma unroll
    for (int n = 0; n < 4; ++n) acc[m][n] = (f32x4)0.0f;

  const int NT = K >> 5;
  STGT(0, 0);
  asm volatile("s_waitcnt vmcnt(0)" ::: "memory");
  __builtin_amdgcn_s_barrier();

  for (int t = 0; t < NT; ++t) {
    const int cur = t & 1;
    const unsigned short* as = lds + (cur << 13);
    const unsigned short* bs = lds + 16384 + (cur << 13);
    if (t + 1 < NT) STGT(cur ^ 1, t + 1);

    __builtin_amdgcn_s_setprio(1);
    bf16x8 af[8], bfr[4];
#pragma unroll
    for (int mi = 0; mi < 8; ++mi)
      af[mi] = *reinterpret_cast<const bf16x8*>(
          &as[((wr << 7) + mi * 16 + r16) * 32 + sgA * 8]);
#pragma unroll
    for (int ni = 0; ni < 4; ++ni)
      bfr[ni] = *reinterpret_cast<const bf16x8*>(
          &bs[(((ni >> 1) << 7) + (wc << 5) + ((ni & 1) << 4) + r16) * 32 + sgA * 8]);
#pragma unroll
    for (int mi = 0; mi < 8; ++mi)
#pragma unroll
      for (int ni = 0; ni < 4; ++ni)
        acc[mi][ni] = __builtin_amdgcn_mfma_f32_16x16x32_bf16(
            af[mi], bfr[ni], acc[mi][ni], 0, 0, 0);
    __builtin_amdgcn_s_setprio(0);
    asm volatile("s_waitcnt vmcnt(0)" ::: "memory");
    __builtin_amdgcn_s_barrier();
  }

  // bf16 epilogue in TWO 64 KiB passes (m 0-3 then 4-7); mapping = r12-verified
  // with per-wave staging halved (rw2 in 0..63; xo key (rw2&12)<<2 identical).
  float bvs[4];
#pragma unroll
  for (int n = 0; n < 4; ++n)
    bvs[n] = bias ? bias[bcol + ((n >> 1) << 7) + (wc << 5) + ((n & 1) << 4) + r16]
                  : 0.0f;
#pragma unroll
  for (int p2 = 0; p2 < 2; ++p2) {
    __syncthreads();
#pragma unroll
    for (int mh = 0; mh < 4; ++mh) {
      int m = p2 * 4 + mh;
#pragma unroll
      for (int r = 0; r < 4; ++r) {
        int rw2 = mh * 16 + kg * 4 + r;
        int xo = (rw2 & 12) << 2;
#pragma unroll
        for (int n = 0; n < 4; ++n) {
          lds[wv * 4096 + rw2 * 64 + ((n * 16 + r16) ^ xo)] =
              f2bf(acc[m][n][r] + bvs[n]);
        }
      }
    }
    __syncthreads();
#pragma unroll
    for (int p = 0; p < 8; ++p) {
      int gl = p * 16 + (tid >> 5);      // 0..127
      int g = tid & 31;
      int wvs = ((gl >> 6) << 2) + ((g >> 2) & 3);
      int row_l = gl & 63;
      int c4g = ((g >> 4) << 5) + ((g & 3) << 3);
      int src = wvs * 4096 + row_l * 64 + (c4g ^ ((row_l & 12) << 2));
      int grow = ((gl >> 6) << 7) + p2 * 64 + row_l;
      u16x8 vv = *reinterpret_cast<const u16x8*>(&lds[src]);
      *reinterpret_cast<u16x8*>(&C[(size_t)(brow + grow) * ldc + bcol + g * 8]) = vv;
    }
  }
}

// ------- 256x256 single-region bf16 GEMM (r12-verified body; Wo path) -------
#define LDA8(mi, sg) (*reinterpret_cast<const bf16x8*>(&as[((wr << 7) + (mi) * 16 + r16) * 64 + (sg) * 8]))
#define LDB8N(nh, ni, sg) (*reinterpret_cast<const bf16x8*>(&bs[(((nh) << 7) + (wc << 5) + (ni) * 16 + r16) * 64 + (sg) * 8]))

template <typename OUT_T>
__global__ __launch_bounds__(512, 2) void gemm8p(
    const unsigned short* __restrict__ A, const unsigned short* __restrict__ B,
    const float* __restrict__ bias, OUT_T* __restrict__ C, int M, int N, int K,
    int ldc) {
  extern __shared__ __align__(16) unsigned short lds[];

  const int tid = threadIdx.x;
  const int lane = tid & 63, wv = tid >> 6;
  const int wr = wv >> 2, wc = wv & 3;
  const int r16 = lane & 15, kg = lane >> 4;
  const int sg0 = (0 * 4 + kg) ^ (r16 & 7);
  const int sg1 = (1 * 4 + kg) ^ (r16 & 7);

  const int xcd = (int)blockIdx.x & 7;
  const int pos = (int)blockIdx.x >> 3;
  const int rpx = (M >> 8) >> 3;
  const int tile_m = xcd * rpx + (pos % rpx);
  const int tile_n = pos / rpx;
  const int brow = tile_m << 8, bcol = tile_n << 8;

  const unsigned short* Ag = A + (size_t)brow * K;
  const unsigned short* Bg = B + (size_t)bcol * K;

  const int sr = tid >> 3;
  const int sc = tid & 7;
  const int sgl = sc ^ (sr & 7);

  auto STG = [&](const unsigned short* G, unsigned short* dstbuf, int row0, int kt) {
    gload_lds16(G + (size_t)(row0 + sr) * K + (size_t)kt * 64 + sgl * 8,
                dstbuf + (row0 + sr) * 64 + sc * 8);
  };
  auto STGT = [&](int pb, int kt) {
    unsigned short* ab = lds + (pb << 14);
    unsigned short* bb = lds + 32768 + (pb << 14);
    STG(Ag, ab, 0, kt);   STG(Ag, ab, 128, kt);
    STG(Ag, ab, 64, kt);  STG(Ag, ab, 192, kt);
    STG(Bg, bb, 0, kt);   STG(Bg, bb, 64, kt);
    STG(Bg, bb, 128, kt); STG(Bg, bb, 192, kt);
  };

  f32x4 acc[8][4];
#pragma unroll
  for (int m = 0; m < 8; ++m)
#pragma unroll
    for (int n = 0; n < 4; ++n) acc[m][n] = (f32x4)0.0f;

  const int NT = K >> 6;
  STGT(0, 0);
  asm volatile("s_waitcnt vmcnt(0)" ::: "memory");
  __builtin_amdgcn_s_barrier();

  for (int t = 0; t < NT; ++t) {
    const int cur = t & 1;
    const unsigned short* as = lds + (cur << 14);
    const unsigned short* bs = lds + 32768 + (cur << 14);
    if (t + 1 < NT) STGT(cur ^ 1, t + 1);

    __builtin_amdgcn_s_setprio(1);
#pragma unroll
    for (int ks = 0; ks < 2; ++ks) {
      const int sg = ks ? sg1 : sg0;
      bf16x8 af[8], bfr[4];
#pragma unroll
      for (int mi = 0; mi < 8; ++mi) af[mi] = LDA8(mi, sg);
#pragma unroll
      for (int ni = 0; ni < 4; ++ni) bfr[ni] = LDB8N(ni >> 1, ni & 1, sg);
#pragma unroll
      for (int mi = 0; mi < 8; ++mi)
#pragma unroll
        for (int ni = 0; ni < 4; ++ni)
          acc[mi][ni] = __builtin_amdgcn_mfma_f32_16x16x32_bf16(
              af[mi], bfr[ni], acc[mi][ni], 0, 0, 0);
    }
    __builtin_amdgcn_s_setprio(0);
    asm volatile("s_waitcnt vmcnt(0)" ::: "memory");
    __builtin_amdgcn_s_barrier();
  }

  // epilogue
  if constexpr (sizeof(OUT_T) == 2) {
    unsigned short* C2 = reinterpret_cast<unsigned short*>(C);
    float bvs[4];
#pragma unroll
    for (int n = 0; n < 4; ++n)
      bvs[n] = bias ? bias[bcol + ((n >> 1) << 7) + (wc << 5) + ((n & 1) << 4) + r16]
                    : 0.0f;
#pragma unroll
    for (int m = 0; m < 8; ++m) {
#pragma unroll
      for (int r = 0; r < 4; ++r) {
        int rw = m * 16 + kg * 4 + r;
        int xo = (rw & 12) << 2;
#pragma unroll
        for (int n = 0; n < 4; ++n) {
          lds[wv * 8192 + rw * 64 + ((n * 16 + r16) ^ xo)] =
              f2bf(acc[m][n][r] + bvs[n]);
        }
      }
    }
    __syncthreads();
#pragma unroll
    for (int p = 0; p < 16; ++p) {
      int grow = p * 16 + (tid >> 5);
      int g = tid & 31;
      int wvs = ((grow >> 7) << 2) + ((g >> 2) & 3);
      int row_l = grow & 127;
      int c4g = ((g >> 4) << 5) + ((g & 3) << 3);
      int src = wvs * 8192 + row_l * 64 + (c4g ^ ((row_l & 12) << 2));
      u16x8 vv = *reinterpret_cast<const u16x8*>(&lds[src]);
      *reinterpret_cast<u16x8*>(&C2[(size_t)(brow + grow) * ldc + bcol + g * 8]) = vv;
    }
  } else {
#pragma unroll
    for (int n = 0; n < 4; ++n) {
      int col = bcol + ((n >> 1) << 7) + (wc << 5) + ((n & 1) << 4) + r16;
      float bv = bias ? bias[col] : 0.0f;
#pragma unroll
      for (int m = 0; m < 8; ++m) {
#pragma unroll
        for (int r = 0; r < 4; ++r) {
          int row = brow + wr * 128 + m * 16 + kg * 4 + r;
          C[(size_t)row * ldc + col] = acc[m][n][r] + bv;
        }
      }
    }
  }
}

// ---------------- k_lin / v_lin partials, b128 K/V reads (r12 verified) ----------------
__global__ __launch_bounds__(256) void kvlin3(
    const unsigned short* __restrict__ qkv,
    const float* __restrict__ E, const float* __restrict__ F,
    float* __restrict__ part) {
  __shared__ __align__(16) unsigned short Ks[128 * 64], Vs[128 * 64];  // 32 KB
  __shared__ float Est[128 * 17], Fst[128 * 17];                       // 17.4 KB
  const int tid = threadIdx.x;
  const int bid = blockIdx.x;
  const int bh = bid >> 3, ns = bid & 7;
  const int b = bh >> 4, h = bh & 15;
  const int k = tid & 15;
  const int dg = (tid >> 4) & 7;
  const int nh = tid >> 7;

  float aK[8] = {0, 0, 0, 0, 0, 0, 0, 0};
  float aV[8] = {0, 0, 0, 0, 0, 0, 0, 0};

  for (int c = 0; c < 4; ++c) {
    int n0 = ns * 512 + c * 128;
#pragma unroll
    for (int it = 0; it < 4; ++it) {
      int f = it * 256 + tid;
      int row = f >> 3, ch = f & 7;
      const unsigned short* gk =
          qkv + (size_t)(b * SEQLEN + n0 + row) * 3072 + 1024 + h * 64 + ch * 8;
      gload_lds16(gk, &Ks[f * 8]);
      gload_lds16(gk + 1024, &Vs[f * 8]);
    }
#pragma unroll
    for (int it = 0; it < 2; ++it) {
      int f = it * 256 + tid;
      int kk = f >> 5, ch = f & 31;
      const float* ep = E + (size_t)(h * 16 + kk) * SEQLEN + n0 + ch * 4;
      const float* fp = F + (size_t)(h * 16 + kk) * SEQLEN + n0 + ch * 4;
      float4 ev = *reinterpret_cast<const float4*>(ep);
      float4 fv = *reinterpret_cast<const float4*>(fp);
      Est[(ch * 4 + 0) * 17 + kk] = ev.x; Est[(ch * 4 + 1) * 17 + kk] = ev.y;
      Est[(ch * 4 + 2) * 17 + kk] = ev.z; Est[(ch * 4 + 3) * 17 + kk] = ev.w;
      Fst[(ch * 4 + 0) * 17 + kk] = fv.x; Fst[(ch * 4 + 1) * 17 + kk] = fv.y;
      Fst[(ch * 4 + 2) * 17 + kk] = fv.z; Fst[(ch * 4 + 3) * 17 + kk] = fv.w;
    }
    __syncthreads();
    for (int n = 0; n < 64; ++n) {
      int nn = nh * 64 + n;
      u16x8 k8 = *reinterpret_cast<const u16x8*>(&Ks[nn * 64 + dg * 8]);
      u16x8 v8 = *reinterpret_cast<const u16x8*>(&Vs[nn * 64 + dg * 8]);
      float ew = Est[nn * 17 + k];
      float fw = Fst[nn * 17 + k];
#pragma unroll
      for (int j = 0; j < 8; ++j) {
        aK[j] += ew * bf2f(k8[j]);
        aV[j] += fw * bf2f(v8[j]);
      }
    }
    __syncthreads();
  }

  float* red = reinterpret_cast<float*>(Ks);
#pragma unroll
  for (int j = 0; j < 8; ++j) {
    red[nh * 1024 + k * 64 + dg * 8 + j] = aK[j];
    red[2048 + nh * 1024 + k * 64 + dg * 8 + j] = aV[j];
  }
  __syncthreads();
  size_t base = ((size_t)ns * 64 + bh) * 2048;
  for (int i = tid; i < 1024; i += 256) {
    part[base + i]        = red[i] + red[1024 + i];
    part[base + 1024 + i] = red[2048 + i] + red[3072 + i];
  }
}

// ---------------- attention (r10/r12 verified) ----------------
__global__ void attn_kernel(const unsigned short* __restrict__ qkv,
                            const float* __restrict__ partKV,
                            unsigned short* __restrict__ aout) {
  __shared__ float kl[1024], vl[1024];
  const int tid = threadIdx.x;
  const int bid = blockIdx.x;
  const int bh = bid >> 4, nt = bid & 15;
  const int b = bh >> 4, h = bh & 15;
  for (int i = tid; i < 1024; i += 256) {
    float sK = 0.0f, sV = 0.0f;
#pragma unroll
    for (int nss = 0; nss < 8; ++nss) {
      size_t base = ((size_t)nss * 64 + bh) * 2048;
      sK += partKV[base + i];
      sV += partKV[base + 1024 + i];
    }
    kl[i] = sK; vl[i] = sV;
  }
  __syncthreads();
  const int n = nt * 256 + tid;
  const unsigned short* qp = qkv + (size_t)(b * SEQLEN + n) * 3072 + h * 64;
  float q[64];
#pragma unroll
  for (int c2 = 0; c2 < 8; ++c2) {
    u16x8 v = *reinterpret_cast<const u16x8*>(qp + c2 * 8);
#pragma unroll
    for (int j = 0; j < 8; ++j) q[c2 * 8 + j] = bf2f(v[j]);
  }
  float s[16];
#pragma unroll
  for (int kq = 0; kq < 16; ++kq) {
    float a = 0;
#pragma unroll
    for (int dd = 0; dd < 64; ++dd) a += q[dd] * kl[kq * 64 + dd];
    s[kq] = a * 0.125f;
  }
  float mx = s[0];
#pragma unroll
  for (int kq = 1; kq < 16; ++kq) mx = fmaxf(mx, s[kq]);
  float sum = 0;
#pragma unroll
  for (int kq = 0; kq < 16; ++kq) { s[kq] = __expf(s[kq] - mx); sum += s[kq]; }
  float inv = 1.0f / sum;
#pragma unroll
  for (int kq = 0; kq < 16; ++kq) s[kq] *= inv;
  unsigned short* op = aout + (size_t)(b * SEQLEN + n) * 1024 + h * 64;
#pragma unroll
  for (int d0 = 0; d0 < 8; ++d0) {
    float o[8] = {0, 0, 0, 0, 0, 0, 0, 0};
#pragma unroll
    for (int kq = 0; kq < 16; ++kq) {
      float p = s[kq];
#pragma unroll
      for (int j = 0; j < 8; ++j) o[j] += p * vl[kq * 64 + d0 * 8 + j];
    }
    u16x8 pk;
#pragma unroll
    for (int j = 0; j < 8; ++j) pk[j] = f2bf(o[j]);
    *reinterpret_cast<u16x8*>(op + d0 * 8) = pk;
  }
}

extern "C" void kernel_launch(void* const* d_in, const int* in_sizes, int n_in,
                              void* d_out, int out_size, void* d_ws, size_t ws_size,
                              hipStream_t stream) {
  const float* x  = (const float*)d_in[0];
  const float* Wq = (const float*)d_in[1];
  const float* bq = (const float*)d_in[2];
  const float* Wk = (const float*)d_in[3];
  const float* bk = (const float*)d_in[4];
  const float* Wv = (const float*)d_in[5];
  const float* bv = (const float*)d_in[6];
  const float* Wo = (const float*)d_in[7];
  const float* bo = (const float*)d_in[8];
  const float* E  = (const float*)d_in[9];
  const float* F  = (const float*)d_in[10];
  float* out = (float*)d_out;

  char* ws = (char*)d_ws;
  unsigned short* Xb   = (unsigned short*)(ws);                // 33,554,432 B
  unsigned short* Wqkv = (unsigned short*)(ws + 33554432);     //  6,291,456 B
  unsigned short* WoB  = (unsigned short*)(ws + 39845888);     //  2,097,152 B
  float*          Bqkv = (float*)(ws + 41943040);              //     12,288 B
  unsigned short* QKV  = (unsigned short*)(ws + 41955328);     // 100,663,296 B
  float*          KVp  = (float*)(ws + 142618624);             //  4,194,304 B -> ends 146,812,928 (known-safe)
  unsigned short* AOut = Xb;  // x-bf16 dead after QKV GEMM; reuse

  (void)hipFuncSetAttribute(reinterpret_cast<const void*>(gemm32),
                            hipFuncAttributeMaxDynamicSharedMemorySize, 65536);
  (void)hipFuncSetAttribute(reinterpret_cast<const void*>(gemm8p<float>),
                            hipFuncAttributeMaxDynamicSharedMemorySize, 131072);

  cvt_all<<<20483, 256, 0, stream>>>(x, Wq, Wk, Wv, Wo, bq, bk, bv,
                                     Xb, Wqkv, WoB, Bqkv);

  // QKV = Xb @ Wqkv^T + Bqkv : [16384, 3072] bf16 ; BK=32, 2 blocks/CU
  gemm32<<<768, 512, 65536, stream>>>(
      Xb, Wqkv, Bqkv, QKV, 16384, 3072, 1024, 3072);

  kvlin3<<<512, 256, 0, stream>>>(QKV, E, F, KVp);
  attn_kernel<<<1024, 256, 0, stream>>>(QKV, KVp, AOut);

  // out = AOut @ Wo^T + bo : [16384, 1024] f32 ; 64x4=256 tiles
  gemm8p<float><<<256, 512, 131072, stream>>>(
      AOut, WoB, bo, out, 16384, 1024, 1024, 1024);
}

// Round 16
// 244.906 us; speedup vs baseline: 4.2192x; 4.2192x over previous
//
#include <hip/hip_runtime.h>
#include <hip/hip_bf16.h>

#define SEQLEN 4096

typedef __bf16 bf16x8 __attribute__((ext_vector_type(8)));
typedef float f32x4 __attribute__((ext_vector_type(4)));
typedef __attribute__((ext_vector_type(8))) unsigned short u16x8;

__device__ inline float bf2f(unsigned short s) {
  union { unsigned u; float f; } t; t.u = ((unsigned)s) << 16; return t.f;
}
__device__ inline unsigned short f2bf(float f) {
  __hip_bfloat16 h = __float2bfloat16(f);
  return *reinterpret_cast<unsigned short*>(&h);
}

__device__ inline void gload_lds16(const void* g, void* l) {
  __builtin_amdgcn_global_load_lds(
      (const __attribute__((address_space(1))) unsigned int*)g,
      (__attribute__((address_space(3))) unsigned int*)l, 16, 0, 0);
}

// ---------------- fused conversion kernel (r10 verified) ----------------
__global__ void cvt_all(const float* __restrict__ x, const float* __restrict__ Wq,
                        const float* __restrict__ Wk, const float* __restrict__ Wv,
                        const float* __restrict__ Wo,
                        const float* __restrict__ bq, const float* __restrict__ bk,
                        const float* __restrict__ bv,
                        unsigned short* __restrict__ Xb,
                        unsigned short* __restrict__ Wqkv,
                        unsigned short* __restrict__ WoB, float* __restrict__ Bqkv) {
  long i = (long)blockIdx.x * 256 + threadIdx.x;
  const float* src;
  unsigned short* dst;
  long rel;
  if (i < 4194304) {            // x -> Xb
    src = x; dst = Xb; rel = i;
  } else if (i < 4456448) {     // Wq
    src = Wq; dst = Wqkv; rel = i - 4194304;
  } else if (i < 4718592) {     // Wk
    src = Wk; dst = Wqkv + 1048576; rel = i - 4456448;
  } else if (i < 4980736) {     // Wv
    src = Wv; dst = Wqkv + 2097152; rel = i - 4718592;
  } else if (i < 5242880) {     // Wo
    src = Wo; dst = WoB; rel = i - 4980736;
  } else if (i < 5243648) {     // bias pack
    long j = i - 5242880;
    const float* bsrc = (j < 256) ? bq : (j < 512) ? bk : bv;
    long jr = j & 255;
    reinterpret_cast<float4*>(Bqkv)[j] =
        reinterpret_cast<const float4*>(bsrc)[jr];
    return;
  } else {
    return;
  }
  float4 v = reinterpret_cast<const float4*>(src)[rel];
  ushort4 o;
  o.x = f2bf(v.x); o.y = f2bf(v.y); o.z = f2bf(v.z); o.w = f2bf(v.w);
  reinterpret_cast<ushort4*>(dst)[rel] = o;
}

// ------- 256x256 single-region bf16 GEMM: C = A @ B^T + bias (r7/r12 verified) -------
#define LDA8(mi, sg) (*reinterpret_cast<const bf16x8*>(&as[((wr << 7) + (mi) * 16 + r16) * 64 + (sg) * 8]))
#define LDB8N(nh, ni, sg) (*reinterpret_cast<const bf16x8*>(&bs[(((nh) << 7) + (wc << 5) + (ni) * 16 + r16) * 64 + (sg) * 8]))

template <typename OUT_T>
__global__ __launch_bounds__(512, 2) void gemm8p(
    const unsigned short* __restrict__ A, const unsigned short* __restrict__ B,
    const float* __restrict__ bias, OUT_T* __restrict__ C, int M, int N, int K,
    int ldc) {
  extern __shared__ __align__(16) unsigned short lds[];

  const int tid = threadIdx.x;
  const int lane = tid & 63, wv = tid >> 6;
  const int wr = wv >> 2, wc = wv & 3;
  const int r16 = lane & 15, kg = lane >> 4;
  const int sg0 = (0 * 4 + kg) ^ (r16 & 7);
  const int sg1 = (1 * 4 + kg) ^ (r16 & 7);

  const int xcd = (int)blockIdx.x & 7;
  const int pos = (int)blockIdx.x >> 3;
  const int rpx = (M >> 8) >> 3;
  const int tile_m = xcd * rpx + (pos % rpx);
  const int tile_n = pos / rpx;
  const int brow = tile_m << 8, bcol = tile_n << 8;

  const unsigned short* Ag = A + (size_t)brow * K;
  const unsigned short* Bg = B + (size_t)bcol * K;

  const int sr = tid >> 3;
  const int sc = tid & 7;
  const int sgl = sc ^ (sr & 7);

  auto STG = [&](const unsigned short* G, unsigned short* dstbuf, int row0, int kt) {
    gload_lds16(G + (size_t)(row0 + sr) * K + (size_t)kt * 64 + sgl * 8,
                dstbuf + (row0 + sr) * 64 + sc * 8);
  };
  auto STGT = [&](int pb, int kt) {
    unsigned short* ab = lds + (pb << 14);
    unsigned short* bb = lds + 32768 + (pb << 14);
    STG(Ag, ab, 0, kt);   STG(Ag, ab, 128, kt);
    STG(Ag, ab, 64, kt);  STG(Ag, ab, 192, kt);
    STG(Bg, bb, 0, kt);   STG(Bg, bb, 64, kt);
    STG(Bg, bb, 128, kt); STG(Bg, bb, 192, kt);
  };

  f32x4 acc[8][4];
#pragma unroll
  for (int m = 0; m < 8; ++m)
#pragma unroll
    for (int n = 0; n < 4; ++n) acc[m][n] = (f32x4)0.0f;

  const int NT = K >> 6;
  STGT(0, 0);
  asm volatile("s_waitcnt vmcnt(0)" ::: "memory");
  __builtin_amdgcn_s_barrier();

  for (int t = 0; t < NT; ++t) {
    const int cur = t & 1;
    const unsigned short* as = lds + (cur << 14);
    const unsigned short* bs = lds + 32768 + (cur << 14);
    if (t + 1 < NT) STGT(cur ^ 1, t + 1);

    __builtin_amdgcn_s_setprio(1);
#pragma unroll
    for (int ks = 0; ks < 2; ++ks) {
      const int sg = ks ? sg1 : sg0;
      bf16x8 af[8], bfr[4];
#pragma unroll
      for (int mi = 0; mi < 8; ++mi) af[mi] = LDA8(mi, sg);
#pragma unroll
      for (int ni = 0; ni < 4; ++ni) bfr[ni] = LDB8N(ni >> 1, ni & 1, sg);
#pragma unroll
      for (int mi = 0; mi < 8; ++mi)
#pragma unroll
        for (int ni = 0; ni < 4; ++ni)
          acc[mi][ni] = __builtin_amdgcn_mfma_f32_16x16x32_bf16(
              af[mi], bfr[ni], acc[mi][ni], 0, 0, 0);
    }
    __builtin_amdgcn_s_setprio(0);
    asm volatile("s_waitcnt vmcnt(0)" ::: "memory");
    __builtin_amdgcn_s_barrier();
  }

  // epilogue
  if constexpr (sizeof(OUT_T) == 2) {
    unsigned short* C2 = reinterpret_cast<unsigned short*>(C);
    float bvs[4];
#pragma unroll
    for (int n = 0; n < 4; ++n)
      bvs[n] = bias ? bias[bcol + ((n >> 1) << 7) + (wc << 5) + ((n & 1) << 4) + r16]
                    : 0.0f;
#pragma unroll
    for (int m = 0; m < 8; ++m) {
#pragma unroll
      for (int r = 0; r < 4; ++r) {
        int rw = m * 16 + kg * 4 + r;
        int xo = (rw & 12) << 2;
#pragma unroll
        for (int n = 0; n < 4; ++n) {
          lds[wv * 8192 + rw * 64 + ((n * 16 + r16) ^ xo)] =
              f2bf(acc[m][n][r] + bvs[n]);
        }
      }
    }
    __syncthreads();
#pragma unroll
    for (int p = 0; p < 16; ++p) {
      int grow = p * 16 + (tid >> 5);
      int g = tid & 31;
      int wvs = ((grow >> 7) << 2) + ((g >> 2) & 3);
      int row_l = grow & 127;
      int c4g = ((g >> 4) << 5) + ((g & 3) << 3);
      int src = wvs * 8192 + row_l * 64 + (c4g ^ ((row_l & 12) << 2));
      u16x8 vv = *reinterpret_cast<const u16x8*>(&lds[src]);
      *reinterpret_cast<u16x8*>(&C2[(size_t)(brow + grow) * ldc + bcol + g * 8]) = vv;
    }
  } else {
#pragma unroll
    for (int n = 0; n < 4; ++n) {
      int col = bcol + ((n >> 1) << 7) + (wc << 5) + ((n & 1) << 4) + r16;
      float bv = bias ? bias[col] : 0.0f;
#pragma unroll
      for (int m = 0; m < 8; ++m) {
#pragma unroll
        for (int r = 0; r < 4; ++r) {
          int row = brow + wr * 128 + m * 16 + kg * 4 + r;
          C[(size_t)row * ldc + col] = acc[m][n][r] + bv;
        }
      }
    }
  }
}

// ---------------- k_lin / v_lin partials, b128 K/V reads (r12 verified) ----------------
__global__ __launch_bounds__(256) void kvlin3(
    const unsigned short* __restrict__ qkv,
    const float* __restrict__ E, const float* __restrict__ F,
    float* __restrict__ part) {
  __shared__ __align__(16) unsigned short Ks[128 * 64], Vs[128 * 64];  // 32 KB
  __shared__ float Est[128 * 17], Fst[128 * 17];                       // 17.4 KB
  const int tid = threadIdx.x;
  const int bid = blockIdx.x;
  const int bh = bid >> 3, ns = bid & 7;
  const int b = bh >> 4, h = bh & 15;
  const int k = tid & 15;
  const int dg = (tid >> 4) & 7;
  const int nh = tid >> 7;

  float aK[8] = {0, 0, 0, 0, 0, 0, 0, 0};
  float aV[8] = {0, 0, 0, 0, 0, 0, 0, 0};

  for (int c = 0; c < 4; ++c) {
    int n0 = ns * 512 + c * 128;
#pragma unroll
    for (int it = 0; it < 4; ++it) {
      int f = it * 256 + tid;
      int row = f >> 3, ch = f & 7;
      const unsigned short* gk =
          qkv + (size_t)(b * SEQLEN + n0 + row) * 3072 + 1024 + h * 64 + ch * 8;
      gload_lds16(gk, &Ks[f * 8]);
      gload_lds16(gk + 1024, &Vs[f * 8]);
    }
#pragma unroll
    for (int it = 0; it < 2; ++it) {
      int f = it * 256 + tid;
      int kk = f >> 5, ch = f & 31;
      const float* ep = E + (size_t)(h * 16 + kk) * SEQLEN + n0 + ch * 4;
      const float* fp = F + (size_t)(h * 16 + kk) * SEQLEN + n0 + ch * 4;
      float4 ev = *reinterpret_cast<const float4*>(ep);
      float4 fv = *reinterpret_cast<const float4*>(fp);
      Est[(ch * 4 + 0) * 17 + kk] = ev.x; Est[(ch * 4 + 1) * 17 + kk] = ev.y;
      Est[(ch * 4 + 2) * 17 + kk] = ev.z; Est[(ch * 4 + 3) * 17 + kk] = ev.w;
      Fst[(ch * 4 + 0) * 17 + kk] = fv.x; Fst[(ch * 4 + 1) * 17 + kk] = fv.y;
      Fst[(ch * 4 + 2) * 17 + kk] = fv.z; Fst[(ch * 4 + 3) * 17 + kk] = fv.w;
    }
    __syncthreads();
    for (int n = 0; n < 64; ++n) {
      int nn = nh * 64 + n;
      u16x8 k8 = *reinterpret_cast<const u16x8*>(&Ks[nn * 64 + dg * 8]);
      u16x8 v8 = *reinterpret_cast<const u16x8*>(&Vs[nn * 64 + dg * 8]);
      float ew = Est[nn * 17 + k];
      float fw = Fst[nn * 17 + k];
#pragma unroll
      for (int j = 0; j < 8; ++j) {
        aK[j] += ew * bf2f(k8[j]);
        aV[j] += fw * bf2f(v8[j]);
      }
    }
    __syncthreads();
  }

  float* red = reinterpret_cast<float*>(Ks);
#pragma unroll
  for (int j = 0; j < 8; ++j) {
    red[nh * 1024 + k * 64 + dg * 8 + j] = aK[j];
    red[2048 + nh * 1024 + k * 64 + dg * 8 + j] = aV[j];
  }
  __syncthreads();
  size_t base = ((size_t)ns * 64 + bh) * 2048;
  for (int i = tid; i < 1024; i += 256) {
    part[base + i]        = red[i] + red[1024 + i];
    part[base + 1024 + i] = red[2048 + i] + red[3072 + i];
  }
}

// ---------------- attention: 8-partial sum + scores -> softmax -> PV (r12 verified) ----------------
__global__ void attn_kernel(const unsigned short* __restrict__ qkv,
                            const float* __restrict__ partKV,
                            unsigned short* __restrict__ aout) {
  __shared__ float kl[1024], vl[1024];
  const int tid = threadIdx.x;
  const int bid = blockIdx.x;
  const int bh = bid >> 4, nt = bid & 15;
  const int b = bh >> 4, h = bh & 15;
  for (int i = tid; i < 1024; i += 256) {
    float sK = 0.0f, sV = 0.0f;
#pragma unroll
    for (int nss = 0; nss < 8; ++nss) {
      size_t base = ((size_t)nss * 64 + bh) * 2048;
      sK += partKV[base + i];
      sV += partKV[base + 1024 + i];
    }
    kl[i] = sK; vl[i] = sV;
  }
  __syncthreads();
  const int n = nt * 256 + tid;
  const unsigned short* qp = qkv + (size_t)(b * SEQLEN + n) * 3072 + h * 64;
  float q[64];
#pragma unroll
  for (int c2 = 0; c2 < 8; ++c2) {
    u16x8 v = *reinterpret_cast<const u16x8*>(qp + c2 * 8);
#pragma unroll
    for (int j = 0; j < 8; ++j) q[c2 * 8 + j] = bf2f(v[j]);
  }
  float s[16];
#pragma unroll
  for (int kq = 0; kq < 16; ++kq) {
    float a = 0;
#pragma unroll
    for (int dd = 0; dd < 64; ++dd) a += q[dd] * kl[kq * 64 + dd];
    s[kq] = a * 0.125f;
  }
  float mx = s[0];
#pragma unroll
  for (int kq = 1; kq < 16; ++kq) mx = fmaxf(mx, s[kq]);
  float sum = 0;
#pragma unroll
  for (int kq = 0; kq < 16; ++kq) { s[kq] = __expf(s[kq] - mx); sum += s[kq]; }
  float inv = 1.0f / sum;
#pragma unroll
  for (int kq = 0; kq < 16; ++kq) s[kq] *= inv;
  unsigned short* op = aout + (size_t)(b * SEQLEN + n) * 1024 + h * 64;
#pragma unroll
  for (int d0 = 0; d0 < 8; ++d0) {
    float o[8] = {0, 0, 0, 0, 0, 0, 0, 0};
#pragma unroll
    for (int kq = 0; kq < 16; ++kq) {
      float p = s[kq];
#pragma unroll
      for (int j = 0; j < 8; ++j) o[j] += p * vl[kq * 64 + d0 * 8 + j];
    }
    u16x8 pk;
#pragma unroll
    for (int j = 0; j < 8; ++j) pk[j] = f2bf(o[j]);
    *reinterpret_cast<u16x8*>(op + d0 * 8) = pk;
  }
}

extern "C" void kernel_launch(void* const* d_in, const int* in_sizes, int n_in,
                              void* d_out, int out_size, void* d_ws, size_t ws_size,
                              hipStream_t stream) {
  const float* x  = (const float*)d_in[0];
  const float* Wq = (const float*)d_in[1];
  const float* bq = (const float*)d_in[2];
  const float* Wk = (const float*)d_in[3];
  const float* bk = (const float*)d_in[4];
  const float* Wv = (const float*)d_in[5];
  const float* bv = (const float*)d_in[6];
  const float* Wo = (const float*)d_in[7];
  const float* bo = (const float*)d_in[8];
  const float* E  = (const float*)d_in[9];
  const float* F  = (const float*)d_in[10];
  float* out = (float*)d_out;

  char* ws = (char*)d_ws;
  unsigned short* Xb   = (unsigned short*)(ws);                // 33,554,432 B
  unsigned short* Wqkv = (unsigned short*)(ws + 33554432);     //  6,291,456 B
  unsigned short* WoB  = (unsigned short*)(ws + 39845888);     //  2,097,152 B
  float*          Bqkv = (float*)(ws + 41943040);              //     12,288 B
  unsigned short* QKV  = (unsigned short*)(ws + 41955328);     // 100,663,296 B
  float*          KVp  = (float*)(ws + 142618624);             //  4,194,304 B -> ends 146,812,928 (known-safe)
  unsigned short* AOut = Xb;  // x-bf16 dead after QKV GEMM; reuse

  (void)hipFuncSetAttribute(reinterpret_cast<const void*>(gemm8p<unsigned short>),
                            hipFuncAttributeMaxDynamicSharedMemorySize, 131072);
  (void)hipFuncSetAttribute(reinterpret_cast<const void*>(gemm8p<float>),
                            hipFuncAttributeMaxDynamicSharedMemorySize, 131072);

  cvt_all<<<20483, 256, 0, stream>>>(x, Wq, Wk, Wv, Wo, bq, bk, bv,
                                     Xb, Wqkv, WoB, Bqkv);

  // QKV = Xb @ Wqkv^T + Bqkv : [16384, 3072] bf16 ; 64x12=768 tiles
  gemm8p<unsigned short><<<768, 512, 131072, stream>>>(
      Xb, Wqkv, Bqkv, QKV, 16384, 3072, 1024, 3072);

  kvlin3<<<512, 256, 0, stream>>>(QKV, E, F, KVp);
  attn_kernel<<<1024, 256, 0, stream>>>(QKV, KVp, AOut);

  // out = AOut @ Wo^T + bo : [16384, 1024] f32 ; 64x4=256 tiles
  gemm8p<float><<<256, 512, 131072, stream>>>(
      AOut, WoB, bo, out, 16384, 1024, 1024, 1024);
}